// Round 2
// baseline (144.302 us; speedup 1.0000x reference)
//
#include <hip/hip_runtime.h>
#include <stdint.h>

#define B_DIM 16384
#define L_DIM 4096
#define H_DIM 256
#define LN_EPS 1e-5f

typedef unsigned short u16;
typedef __attribute__((ext_vector_type(4))) float f32x4;
typedef __attribute__((ext_vector_type(8))) short short8;

__device__ __forceinline__ u16 f2bf(float f) {
  union { float f; uint32_t u; } v; v.f = f;
  uint32_t u = v.u;
  u += 0x7FFFu + ((u >> 16) & 1u);   // round-to-nearest-even
  return (u16)(u >> 16);
}

__device__ __forceinline__ void gload_lds16(const void* g, void* l) {
  __builtin_amdgcn_global_load_lds((const __attribute__((address_space(1))) void*)g,
                                   (__attribute__((address_space(3))) void*)l, 16, 0, 0);
}

// featT fragment-major prep:
// fragB[((kstep*16 + nt)*64 + lane)*8 + j] = bf16(emb[gidx[kstep*32+(lane>>4)*8+j]][nt*16+(lane&15)])
// One wave per fragment; 2048 fragments total (128 ksteps x 16 ntiles).
__global__ __launch_bounds__(256) void prep_frag(const float* __restrict__ emb,
                                                 const int* __restrict__ gidx,
                                                 u16* __restrict__ fragB) {
  const int t = threadIdx.x;
  const int l = t & 63;
  const int w = t >> 6;
  const int frag = blockIdx.x * 4 + w;       // 0..2047
  const int kstep = frag >> 4;               // 0..127
  const int nt = frag & 15;
  const int n = nt * 16 + (l & 15);
  const int kbase = kstep * 32 + (l >> 4) * 8;
  short8 v;
#pragma unroll
  for (int j = 0; j < 8; ++j) {
    const int g = gidx[kbase + j];
    v[j] = (short)f2bf(emb[(size_t)g * H_DIM + n]);
  }
  *reinterpret_cast<short8*>(fragB + ((size_t)frag * 64 + l) * 8) = v;
}

// dst[n][k ^ ((n&7)<<3)] = bf16(src[k][n])  — transpose+cast+pre-swizzle (for gemm2's W1)
__global__ __launch_bounds__(256) void prep_tr(const float* __restrict__ src,
                                               const int* __restrict__ idx,
                                               u16* __restrict__ dst,
                                               int Ktot, int srcW) {
  __shared__ u16 tile[64][66];
  const int t = threadIdx.x;
  const int k0 = blockIdx.x * 64;
  const int n0 = blockIdx.y * 64;
  for (int r0 = 0; r0 < 64; r0 += 4) {
    const int kk = k0 + r0 + (t >> 6);
    const int nn = n0 + (t & 63);
    const int srow = idx ? idx[kk] : kk;
    tile[r0 + (t >> 6)][t & 63] = f2bf(src[(size_t)srow * srcW + nn]);
  }
  __syncthreads();
  for (int c = t; c < 512; c += 256) {
    const int n = c >> 3;
    const int inner = c & 7;
    const int nG = n0 + n;
    short8 v;
#pragma unroll
    for (int j = 0; j < 8; ++j) v[j] = (short)tile[inner * 8 + j][n];
    const size_t didx = (size_t)nG * Ktot + (size_t)k0 +
                        (size_t)((inner * 8) ^ ((nG & 7) << 3));
    *reinterpret_cast<short8*>(dst + didx) = v;
  }
}

// GEMM1: h[16384,256] = x[16384,4096](fp32->bf16) @ feat (bf16, fragment-major fragB).
// BM=64, 512 thr = 8 waves laid out 4(m) x 2(k-half). Each wave: 16 private rows,
// all 256 cols, half the K of each BK=64 stage. A: global->reg (private rows, no LDS,
// no sharing). B: double-buffered LDS via linear global_load_lds of fragment-major
// data (conflict-free contiguous ds_read_b128). Raw s_barrier + vmcnt(0) only at the
// stage top: loads issued after it stay in flight a full stage (~1.5k cy > HBM lat).
__global__ __launch_bounds__(512, 2) void gemm1(const float* __restrict__ x,
                                                const u16* __restrict__ fragB,
                                                u16* __restrict__ h_s) {
  __shared__ __align__(16) u16 ldsB[2 * 32 * 512];   // 2 x 32KB (16 ntiles x 2 ksteps x 1KB)
  __shared__ float red[64][273];                     // wk-reduction, odd stride: conflict-free
  const int t = threadIdx.x;
  const int l = t & 63;
  const int w = t >> 6;
  const int wm = w >> 1;          // 0..3  : m-slice (16 rows)
  const int wk = w & 1;           // 0..1  : k-half of each stage
  const int m0 = blockIdx.x * 64;

  const float* xrow = x + (size_t)(m0 + wm * 16 + (l & 15)) * L_DIM
                        + wk * 32 + ((l >> 4) * 8);

  f32x4 acc[16] = {};

  // prologue: issue stage-0 B gloads + A loads
#pragma unroll
  for (int i = 0; i < 4; ++i) {
    const int j = w * 4 + i;                       // frag 0..31 of stage 0
    gload_lds16(fragB + ((size_t)((j >> 4) * 16 + (j & 15)) * 64 + l) * 8,
                ldsB + j * 512);
  }
  float4 aN0 = *(const float4*)(xrow);
  float4 aN1 = *(const float4*)(xrow + 4);
  float4 aC0, aC1;

  for (int s = 0; s < 64; ++s) {
    // everything issued last stage had a full stage in flight; drain own, then sync
    asm volatile("s_waitcnt vmcnt(0)" ::: "memory");
    aC0 = aN0; aC1 = aN1;
    __builtin_amdgcn_s_barrier();                  // buf[s&1] fully written, all waves
    if (s < 63) {
      const int nx = s + 1;
      u16* dst = ldsB + (nx & 1) * 16384;
      const u16* srcB = fragB + (size_t)(nx * 2) * 16 * 512;   // kstep base = nx*2
#pragma unroll
      for (int i = 0; i < 4; ++i) {
        const int j = w * 4 + i;
        gload_lds16(srcB + ((size_t)((j >> 4) * 16 + (j & 15)) * 64 + l) * 8,
                    dst + j * 512);
      }
      aN0 = *(const float4*)(xrow + nx * 64);
      aN1 = *(const float4*)(xrow + nx * 64 + 4);
    }
    // compute stage s: convert A, 16 independent MFMAs (one per ntile)
    short8 af;
    af[0] = (short)f2bf(aC0.x); af[1] = (short)f2bf(aC0.y);
    af[2] = (short)f2bf(aC0.z); af[3] = (short)f2bf(aC0.w);
    af[4] = (short)f2bf(aC1.x); af[5] = (short)f2bf(aC1.y);
    af[6] = (short)f2bf(aC1.z); af[7] = (short)f2bf(aC1.w);
    const u16* bb = ldsB + (s & 1) * 16384 + (wk * 16) * 512 + l * 8;
#pragma unroll
    for (int nt = 0; nt < 16; ++nt) {
      const short8 bf = *reinterpret_cast<const short8*>(bb + nt * 512);
      acc[nt] = __builtin_amdgcn_mfma_f32_16x16x32_bf16(af, bf, acc[nt], 0, 0, 0);
    }
    asm volatile("s_waitcnt lgkmcnt(0)" ::: "memory");
    __builtin_amdgcn_s_barrier();                  // reads done; next stage may overwrite
  }

  // epilogue: combine the two k-halves, write h_s pre-swizzled for gemm2
  __syncthreads();
  if (wk == 1) {
#pragma unroll
    for (int nt = 0; nt < 16; ++nt)
#pragma unroll
      for (int r = 0; r < 4; ++r)
        red[wm * 16 + (l >> 4) * 4 + r][nt * 16 + (l & 15)] = acc[nt][r];
  }
  __syncthreads();
  if (wk == 0) {
#pragma unroll
    for (int r = 0; r < 4; ++r) {
      const int row_l = (l >> 4) * 4 + r;
      const int row_g = m0 + wm * 16 + row_l;
      const int swz = (row_g & 7) << 3;
      u16* hp = h_s + (size_t)row_g * H_DIM;
#pragma unroll
      for (int nt = 0; nt < 16; ++nt) {
        const int col = nt * 16 + (l & 15);
        const float sum = acc[nt][r] + red[wm * 16 + row_l][col];
        hp[col ^ swz] = f2bf(sum);
      }
    }
  }
}

// out = LayerNorm(relu(h @ W1 + b1)) * gamma + beta   (unchanged from passing round)
__global__ __launch_bounds__(256, 1) void gemm2_ln(const u16* __restrict__ h_s,
                                                   const u16* __restrict__ w1T,
                                                   const float* __restrict__ b1,
                                                   const float* __restrict__ gmm,
                                                   const float* __restrict__ bta,
                                                   float* __restrict__ out) {
  __shared__ __align__(16) u16 As[64 * 64];
  __shared__ __align__(16) u16 Bs[256 * 64];
  __shared__ float red_s[4][64];
  __shared__ float red_q[4][64];
  __shared__ float mean_s[64];
  __shared__ float rstd_s[64];
  const int t = threadIdx.x;
  const int lane = t & 63;
  const int w = t >> 6;
  const int m0 = blockIdx.x * 64;
  const int bn = t >> 3;
  const int binner = (t & 7) * 8;

  f32x4 acc[4][4] = {};
  for (int kt = 0; kt < 4; ++kt) {
    __syncthreads();
#pragma unroll
    for (int r = 0; r < 2; ++r) {
      const u16* gp = h_s + (size_t)(m0 + r * 32 + bn) * H_DIM + kt * 64 + binner;
      gload_lds16(gp, &As[(r * 256 + w * 64) * 8]);
    }
#pragma unroll
    for (int r = 0; r < 8; ++r) {
      const u16* gp = w1T + (size_t)(r * 32 + bn) * H_DIM + kt * 64 + binner;
      gload_lds16(gp, &Bs[(r * 256 + w * 64) * 8]);
    }
    __syncthreads();
#pragma unroll
    for (int ks = 0; ks < 2; ++ks) {
      const int kb = ks * 64 + ((lane >> 4) * 16);
      short8 af[4], bf[4];
#pragma unroll
      for (int mi = 0; mi < 4; ++mi) {
        const int row = mi * 16 + (lane & 15);
        af[mi] = *reinterpret_cast<const short8*>(
            reinterpret_cast<const char*>(As) + row * 128 + (kb ^ ((row & 7) << 4)));
      }
#pragma unroll
      for (int ni = 0; ni < 4; ++ni) {
        const int n = w * 64 + ni * 16 + (lane & 15);
        bf[ni] = *reinterpret_cast<const short8*>(
            reinterpret_cast<const char*>(Bs) + n * 128 + (kb ^ ((n & 7) << 4)));
      }
#pragma unroll
      for (int mi = 0; mi < 4; ++mi)
#pragma unroll
        for (int ni = 0; ni < 4; ++ni)
          acc[mi][ni] = __builtin_amdgcn_mfma_f32_16x16x32_bf16(af[mi], bf[ni], acc[mi][ni], 0, 0, 0);
    }
  }
  const int cbase = w * 64 + (lane & 15);
  float cb[4];
#pragma unroll
  for (int ni = 0; ni < 4; ++ni) cb[ni] = b1[cbase + ni * 16];
#pragma unroll
  for (int mi = 0; mi < 4; ++mi)
#pragma unroll
    for (int ni = 0; ni < 4; ++ni)
#pragma unroll
      for (int r = 0; r < 4; ++r)
        acc[mi][ni][r] = fmaxf(acc[mi][ni][r] + cb[ni], 0.0f);
#pragma unroll
  for (int mi = 0; mi < 4; ++mi) {
#pragma unroll
    for (int r = 0; r < 4; ++r) {
      float s = 0.f, q = 0.f;
#pragma unroll
      for (int ni = 0; ni < 4; ++ni) { const float v = acc[mi][ni][r]; s += v; q += v * v; }
#pragma unroll
      for (int msk = 1; msk < 16; msk <<= 1) { s += __shfl_xor(s, msk); q += __shfl_xor(q, msk); }
      if ((lane & 15) == 0) {
        const int row = mi * 16 + (lane >> 4) * 4 + r;
        red_s[w][row] = s;
        red_q[w][row] = q;
      }
    }
  }
  __syncthreads();
  if (t < 64) {
    const float s = red_s[0][t] + red_s[1][t] + red_s[2][t] + red_s[3][t];
    const float q = red_q[0][t] + red_q[1][t] + red_q[2][t] + red_q[3][t];
    const float mu = s * (1.0f / 256.0f);
    const float var = q * (1.0f / 256.0f) - mu * mu;
    mean_s[t] = mu;
    rstd_s[t] = rsqrtf(var + LN_EPS);
  }
  __syncthreads();
  float cg[4], cbt[4];
#pragma unroll
  for (int ni = 0; ni < 4; ++ni) { cg[ni] = gmm[cbase + ni * 16]; cbt[ni] = bta[cbase + ni * 16]; }
#pragma unroll
  for (int mi = 0; mi < 4; ++mi) {
#pragma unroll
    for (int r = 0; r < 4; ++r) {
      const int row = mi * 16 + (lane >> 4) * 4 + r;
      const float mu = mean_s[row];
      const float rs = rstd_s[row];
      float* op = out + (size_t)(m0 + row) * H_DIM;
#pragma unroll
      for (int ni = 0; ni < 4; ++ni)
        op[cbase + ni * 16] = cg[ni] * (acc[mi][ni][r] - mu) * rs + cbt[ni];
    }
  }
}

extern "C" void kernel_launch(void* const* d_in, const int* in_sizes, int n_in,
                              void* d_out, int out_size, void* d_ws, size_t ws_size,
                              hipStream_t stream) {
  const float* x    = (const float*)d_in[0];
  const float* emb  = (const float*)d_in[1];
  const float* W1   = (const float*)d_in[2];
  const float* b1   = (const float*)d_in[3];
  const float* gmm  = (const float*)d_in[4];
  const float* bta  = (const float*)d_in[5];
  const int*   gidx = (const int*)d_in[6];
  float* out = (float*)d_out;

  char* ws = (char*)d_ws;
  u16* fragB = (u16*)ws;                                            // [128][16][64][8] bf16, 2 MB
  u16* w1T   = (u16*)(ws + (size_t)H_DIM * L_DIM * 2);              // [256][256]  bf16, 128 KB
  u16* h_s   = (u16*)(ws + (size_t)H_DIM * L_DIM * 2
                          + (size_t)H_DIM * H_DIM * 2);             // [16384][256] bf16, 8 MB

  prep_frag<<<512, 256, 0, stream>>>(emb, gidx, fragB);
  prep_tr<<<dim3(H_DIM / 64, H_DIM / 64), 256, 0, stream>>>(W1, nullptr, w1T, H_DIM, H_DIM);
  gemm1<<<dim3(B_DIM / 64), 512, 0, stream>>>(x, fragB, h_s);
  gemm2_ln<<<dim3(B_DIM / 64), 256, 0, stream>>>(h_s, w1T, b1, gmm, bta, out);
}

// Round 3
// 123.288 us; speedup vs baseline: 1.1704x; 1.1704x over previous
//
#include <hip/hip_runtime.h>
#include <stdint.h>

#define B_DIM 16384
#define L_DIM 4096
#define H_DIM 256
#define LN_EPS 1e-5f

typedef unsigned short u16;
typedef __attribute__((ext_vector_type(4))) float f32x4;
typedef __attribute__((ext_vector_type(8))) short short8;

__device__ __forceinline__ u16 f2bf(float f) {
  union { float f; uint32_t u; } v; v.f = f;
  uint32_t u = v.u;
  u += 0x7FFFu + ((u >> 16) & 1u);   // round-to-nearest-even
  return (u16)(u >> 16);
}

__device__ __forceinline__ void gload_lds16(const void* g, void* l) {
  __builtin_amdgcn_global_load_lds((const __attribute__((address_space(1))) void*)g,
                                   (__attribute__((address_space(3))) void*)l, 16, 0, 0);
}

// featT fragment-major prep:
// fragB[((kstep*16 + nt)*64 + lane)*8 + j] = bf16(emb[gidx[kstep*32+(lane>>4)*8+j]][nt*16+(lane&15)])
__global__ __launch_bounds__(256) void prep_frag(const float* __restrict__ emb,
                                                 const int* __restrict__ gidx,
                                                 u16* __restrict__ fragB) {
  const int t = threadIdx.x;
  const int l = t & 63;
  const int w = t >> 6;
  const int frag = blockIdx.x * 4 + w;       // 0..2047
  const int kstep = frag >> 4;               // 0..127
  const int nt = frag & 15;
  const int n = nt * 16 + (l & 15);
  const int kbase = kstep * 32 + (l >> 4) * 8;
  short8 v;
#pragma unroll
  for (int j = 0; j < 8; ++j) {
    const int g = gidx[kbase + j];
    v[j] = (short)f2bf(emb[(size_t)g * H_DIM + n]);
  }
  *reinterpret_cast<short8*>(fragB + ((size_t)frag * 64 + l) * 8) = v;
}

// dst[n][k ^ ((n&7)<<3)] = bf16(src[k][n])  — transpose+cast+pre-swizzle (for gemm2's W1)
__global__ __launch_bounds__(256) void prep_tr(const float* __restrict__ src,
                                               const int* __restrict__ idx,
                                               u16* __restrict__ dst,
                                               int Ktot, int srcW) {
  __shared__ u16 tile[64][66];
  const int t = threadIdx.x;
  const int k0 = blockIdx.x * 64;
  const int n0 = blockIdx.y * 64;
  for (int r0 = 0; r0 < 64; r0 += 4) {
    const int kk = k0 + r0 + (t >> 6);
    const int nn = n0 + (t & 63);
    const int srow = idx ? idx[kk] : kk;
    tile[r0 + (t >> 6)][t & 63] = f2bf(src[(size_t)srow * srcW + nn]);
  }
  __syncthreads();
  for (int c = t; c < 512; c += 256) {
    const int n = c >> 3;
    const int inner = c & 7;
    const int nG = n0 + n;
    short8 v;
#pragma unroll
    for (int j = 0; j < 8; ++j) v[j] = (short)tile[inner * 8 + j][n];
    const size_t didx = (size_t)nG * Ktot + (size_t)k0 +
                        (size_t)((inner * 8) ^ ((nG & 7) << 3));
    *reinterpret_cast<short8*>(dst + didx) = v;
  }
}

// GEMM1: h[16384,256] = x[16384,4096](fp32->bf16) @ feat (fragment-major fragB).
// BM=32, BN=256(full), BK=64. 256 thr = 4 waves (2m x 2k). grid=512, 80KB LDS
// -> 2 blocks/CU (cross-block wave overlap per SIMD, dispatch-skew robust).
// ALL global traffic wave-contiguous: A f32 tile staged via global_load_lds
// (source pre-XOR-swizzled at 16B granularity; swizzled ds_read_b128 back,
// fp32->bf16 convert in regs). B fragment-major, linear, conflict-free.
// 2-phase: loads for s+1 issued right after top barrier, vmcnt(0) at top only.
__global__ __launch_bounds__(256, 2) void gemm1(const float* __restrict__ x,
                                                const u16* __restrict__ fragB,
                                                u16* __restrict__ h_s) {
  __shared__ __align__(16) char pool[81920];   // B: 2x32KB @0, A: 2x8KB @65536
  const int t = threadIdx.x;
  const int l = t & 63;
  const int w = t >> 6;
  const int wm = w >> 1;          // m-slice (16 rows)
  const int wk = w & 1;           // k-half of each BK=64 stage
  const int m0 = blockIdx.x * 32;
  const float* xbase = x + (size_t)m0 * L_DIM;

  f32x4 acc[16] = {};

  // prologue: stage-0 loads
#pragma unroll
  for (int i = 0; i < 2; ++i) {
    const int R = (w * 2 + i) * 4 + (l >> 4);            // LDS A row 0..31
    const int c16 = (l & 15) ^ ((R & 7) << 1);           // pre-swizzled src slot
    gload_lds16(xbase + (size_t)R * L_DIM + c16 * 4,
                pool + 65536 + (w * 2 + i) * 1024);
  }
#pragma unroll
  for (int i = 0; i < 8; ++i) {
    const int j = w * 8 + i;                             // frag 0..31 of stage 0
    gload_lds16(fragB + ((size_t)((j >> 4) * 16 + (j & 15)) * 64 + l) * 8,
                pool + j * 1024);
  }

  for (int s = 0; s < 64; ++s) {
    asm volatile("s_waitcnt vmcnt(0)" ::: "memory");     // stage-s loads done
    __builtin_amdgcn_s_barrier();                        // all waves: buf ready
    __builtin_amdgcn_sched_barrier(0);
    if (s < 63) {
      const int nx = s + 1, nb = nx & 1;
#pragma unroll
      for (int i = 0; i < 2; ++i) {
        const int R = (w * 2 + i) * 4 + (l >> 4);
        const int c16 = (l & 15) ^ ((R & 7) << 1);
        gload_lds16(xbase + (size_t)R * L_DIM + nx * 64 + c16 * 4,
                    pool + 65536 + nb * 8192 + (w * 2 + i) * 1024);
      }
      const u16* srcB = fragB + (size_t)(nx * 2) * 16 * 512;
#pragma unroll
      for (int i = 0; i < 8; ++i) {
        const int j = w * 8 + i;
        gload_lds16(srcB + ((size_t)((j >> 4) * 16 + (j & 15)) * 64 + l) * 8,
                    pool + nb * 32768 + j * 1024);
      }
    }
    // compute stage s from buf (s&1)
    const int cb = s & 1;
    const int row = wm * 16 + (l & 15);
    const int abyte = (wk * 128 + (l >> 4) * 32) ^ ((row & 7) << 5);
    const float* ap = (const float*)(pool + 65536 + cb * 8192 + row * 256 + abyte);
    const float4 a0 = *(const float4*)ap;
    const float4 a1 = *(const float4*)(ap + 4);
    short8 af;
    af[0] = (short)f2bf(a0.x); af[1] = (short)f2bf(a0.y);
    af[2] = (short)f2bf(a0.z); af[3] = (short)f2bf(a0.w);
    af[4] = (short)f2bf(a1.x); af[5] = (short)f2bf(a1.y);
    af[6] = (short)f2bf(a1.z); af[7] = (short)f2bf(a1.w);
    const u16* bb = (const u16*)(pool + cb * 32768) + (wk * 16) * 512 + l * 8;
#pragma unroll
    for (int nt = 0; nt < 16; ++nt) {
      const short8 bf = *reinterpret_cast<const short8*>(bb + nt * 512);
      acc[nt] = __builtin_amdgcn_mfma_f32_16x16x32_bf16(af, bf, acc[nt], 0, 0, 0);
    }
    asm volatile("s_waitcnt lgkmcnt(0)" ::: "memory");   // reads done before next writes
    __builtin_amdgcn_s_barrier();
  }

  // epilogue: combine k-halves via LDS (alias pool), write h_s pre-swizzled
  float* red = (float*)pool;                             // [32][260] f32
  __syncthreads();
  if (wk == 1) {
#pragma unroll
    for (int nt = 0; nt < 16; ++nt)
#pragma unroll
      for (int r = 0; r < 4; ++r)
        red[(wm * 16 + (l >> 4) * 4 + r) * 260 + nt * 16 + (l & 15)] = acc[nt][r];
  }
  __syncthreads();
  if (wk == 0) {
#pragma unroll
    for (int r = 0; r < 4; ++r) {
      const int row_l = wm * 16 + (l >> 4) * 4 + r;
      const int row_g = m0 + row_l;
      const int swz = (row_g & 7) << 3;
      u16* hp = h_s + (size_t)row_g * H_DIM;
#pragma unroll
      for (int nt = 0; nt < 16; ++nt) {
        const int col = nt * 16 + (l & 15);
        hp[col ^ swz] = f2bf(acc[nt][r] + red[row_l * 260 + col]);
      }
    }
  }
}

// out = LayerNorm(relu(h @ W1 + b1)) * gamma + beta   (unchanged, passing)
__global__ __launch_bounds__(256, 1) void gemm2_ln(const u16* __restrict__ h_s,
                                                   const u16* __restrict__ w1T,
                                                   const float* __restrict__ b1,
                                                   const float* __restrict__ gmm,
                                                   const float* __restrict__ bta,
                                                   float* __restrict__ out) {
  __shared__ __align__(16) u16 As[64 * 64];
  __shared__ __align__(16) u16 Bs[256 * 64];
  __shared__ float red_s[4][64];
  __shared__ float red_q[4][64];
  __shared__ float mean_s[64];
  __shared__ float rstd_s[64];
  const int t = threadIdx.x;
  const int lane = t & 63;
  const int w = t >> 6;
  const int m0 = blockIdx.x * 64;
  const int bn = t >> 3;
  const int binner = (t & 7) * 8;

  f32x4 acc[4][4] = {};
  for (int kt = 0; kt < 4; ++kt) {
    __syncthreads();
#pragma unroll
    for (int r = 0; r < 2; ++r) {
      const u16* gp = h_s + (size_t)(m0 + r * 32 + bn) * H_DIM + kt * 64 + binner;
      gload_lds16(gp, &As[(r * 256 + w * 64) * 8]);
    }
#pragma unroll
    for (int r = 0; r < 8; ++r) {
      const u16* gp = w1T + (size_t)(r * 32 + bn) * H_DIM + kt * 64 + binner;
      gload_lds16(gp, &Bs[(r * 256 + w * 64) * 8]);
    }
    __syncthreads();
#pragma unroll
    for (int ks = 0; ks < 2; ++ks) {
      const int kb = ks * 64 + ((lane >> 4) * 16);
      short8 af[4], bf[4];
#pragma unroll
      for (int mi = 0; mi < 4; ++mi) {
        const int row = mi * 16 + (lane & 15);
        af[mi] = *reinterpret_cast<const short8*>(
            reinterpret_cast<const char*>(As) + row * 128 + (kb ^ ((row & 7) << 4)));
      }
#pragma unroll
      for (int ni = 0; ni < 4; ++ni) {
        const int n = w * 64 + ni * 16 + (lane & 15);
        bf[ni] = *reinterpret_cast<const short8*>(
            reinterpret_cast<const char*>(Bs) + n * 128 + (kb ^ ((n & 7) << 4)));
      }
#pragma unroll
      for (int mi = 0; mi < 4; ++mi)
#pragma unroll
        for (int ni = 0; ni < 4; ++ni)
          acc[mi][ni] = __builtin_amdgcn_mfma_f32_16x16x32_bf16(af[mi], bf[ni], acc[mi][ni], 0, 0, 0);
    }
  }
  const int cbase = w * 64 + (lane & 15);
  float cb[4];
#pragma unroll
  for (int ni = 0; ni < 4; ++ni) cb[ni] = b1[cbase + ni * 16];
#pragma unroll
  for (int mi = 0; mi < 4; ++mi)
#pragma unroll
    for (int ni = 0; ni < 4; ++ni)
#pragma unroll
      for (int r = 0; r < 4; ++r)
        acc[mi][ni][r] = fmaxf(acc[mi][ni][r] + cb[ni], 0.0f);
#pragma unroll
  for (int mi = 0; mi < 4; ++mi) {
#pragma unroll
    for (int r = 0; r < 4; ++r) {
      float s = 0.f, q = 0.f;
#pragma unroll
      for (int ni = 0; ni < 4; ++ni) { const float v = acc[mi][ni][r]; s += v; q += v * v; }
#pragma unroll
      for (int msk = 1; msk < 16; msk <<= 1) { s += __shfl_xor(s, msk); q += __shfl_xor(q, msk); }
      if ((lane & 15) == 0) {
        const int row = mi * 16 + (lane >> 4) * 4 + r;
        red_s[w][row] = s;
        red_q[w][row] = q;
      }
    }
  }
  __syncthreads();
  if (t < 64) {
    const float s = red_s[0][t] + red_s[1][t] + red_s[2][t] + red_s[3][t];
    const float q = red_q[0][t] + red_q[1][t] + red_q[2][t] + red_q[3][t];
    const float mu = s * (1.0f / 256.0f);
    const float var = q * (1.0f / 256.0f) - mu * mu;
    mean_s[t] = mu;
    rstd_s[t] = rsqrtf(var + LN_EPS);
  }
  __syncthreads();
  float cg[4], cbt[4];
#pragma unroll
  for (int ni = 0; ni < 4; ++ni) { cg[ni] = gmm[cbase + ni * 16]; cbt[ni] = bta[cbase + ni * 16]; }
#pragma unroll
  for (int mi = 0; mi < 4; ++mi) {
#pragma unroll
    for (int r = 0; r < 4; ++r) {
      const int row = mi * 16 + (lane >> 4) * 4 + r;
      const float mu = mean_s[row];
      const float rs = rstd_s[row];
      float* op = out + (size_t)(m0 + row) * H_DIM;
#pragma unroll
      for (int ni = 0; ni < 4; ++ni)
        op[cbase + ni * 16] = cg[ni] * (acc[mi][ni][r] - mu) * rs + cbt[ni];
    }
  }
}

extern "C" void kernel_launch(void* const* d_in, const int* in_sizes, int n_in,
                              void* d_out, int out_size, void* d_ws, size_t ws_size,
                              hipStream_t stream) {
  const float* x    = (const float*)d_in[0];
  const float* emb  = (const float*)d_in[1];
  const float* W1   = (const float*)d_in[2];
  const float* b1   = (const float*)d_in[3];
  const float* gmm  = (const float*)d_in[4];
  const float* bta  = (const float*)d_in[5];
  const int*   gidx = (const int*)d_in[6];
  float* out = (float*)d_out;

  char* ws = (char*)d_ws;
  u16* fragB = (u16*)ws;                                            // [128][16][64][8] bf16, 2 MB
  u16* w1T   = (u16*)(ws + (size_t)H_DIM * L_DIM * 2);              // [256][256]  bf16, 128 KB
  u16* h_s   = (u16*)(ws + (size_t)H_DIM * L_DIM * 2
                          + (size_t)H_DIM * H_DIM * 2);             // [16384][256] bf16, 8 MB

  prep_frag<<<512, 256, 0, stream>>>(emb, gidx, fragB);
  prep_tr<<<dim3(H_DIM / 64, H_DIM / 64), 256, 0, stream>>>(W1, nullptr, w1T, H_DIM, H_DIM);
  gemm1<<<dim3(B_DIM / 32), 256, 0, stream>>>(x, fragB, h_s);
  gemm2_ln<<<dim3(B_DIM / 64), 256, 0, stream>>>(h_s, w1T, b1, gmm, bta, out);
}

// Round 6
// 112.675 us; speedup vs baseline: 1.2807x; 1.0942x over previous
//
#include <hip/hip_runtime.h>
#include <stdint.h>

#define B_DIM 16384
#define L_DIM 4096
#define H_DIM 256
#define LN_EPS 1e-5f
// bijective 4-bit slot permutation from the low 4 row bits
#define PERM4(r) ((((r) & 7) << 1) | (((r) >> 3) & 1))

typedef unsigned short u16;
typedef __attribute__((ext_vector_type(4))) float f32x4;
typedef __attribute__((ext_vector_type(8))) short short8;

__device__ __forceinline__ u16 f2bf(float f) {
  union { float f; uint32_t u; } v; v.f = f;
  uint32_t u = v.u;
  u += 0x7FFFu + ((u >> 16) & 1u);   // round-to-nearest-even
  return (u16)(u >> 16);
}

__device__ __forceinline__ void gload_lds16(const void* g, void* l) {
  __builtin_amdgcn_global_load_lds((const __attribute__((address_space(1))) void*)g,
                                   (__attribute__((address_space(3))) void*)l, 16, 0, 0);
}

// Fragment-major prep (works for gathered emb and for plain W1):
// frag = kstep*16 + nt;  dst[frag][lane][j] = bf16(src[row][nt*16 + (lane&15)])
// row = idx ? idx[kstep*32 + (lane>>4)*8 + j] : (kstep*32 + (lane>>4)*8 + j)
__global__ __launch_bounds__(256) void prep_frag(const float* __restrict__ src,
                                                 const int* __restrict__ idx,
                                                 u16* __restrict__ dst) {
  const int t = threadIdx.x;
  const int l = t & 63;
  const int w = t >> 6;
  const int frag = blockIdx.x * 4 + w;
  const int kstep = frag >> 4;
  const int nt = frag & 15;
  const int n = nt * 16 + (l & 15);
  const int kbase = kstep * 32 + (l >> 4) * 8;
  short8 v;
#pragma unroll
  for (int j = 0; j < 8; ++j) {
    const int k = kbase + j;
    const int g = idx ? idx[k] : k;
    v[j] = (short)f2bf(src[(size_t)g * H_DIM + n]);
  }
  *reinterpret_cast<short8*>(dst + ((size_t)frag * 64 + l) * 8) = v;
}

// Fused: h = x @ feat (bf16 MFMA, K=4096), then out = LN(relu(h @ W1 + b1)).
// BM=64, 512 thr = 8 waves (wm 0..3 x wn 0..1): wave owns 16 rows x 128 cols.
// x: global_load_lds depth-2 prefetch (3 bufs, vmcnt(2) at stage top).
// B: fragment-major, depth-1 double buffer (L2/L3-resident).
// NOTE (R5 bug): global_load_lds's global SOURCE is per-lane — every staging
// address must include the lane term (+ l*8 u16 here). A wave-uniform source
// makes all 64 lanes fetch the same 16 bytes (LDS dest auto-advances, source
// does not). sched_barrier(0) fences additionally pin VMEM issue order so the
// counted vmcnt(2) at the stage top is exact.
// GEMM2: h tile lives in LDS only; W1 fragment-major 4-stage loop; LN fused.
__global__ __launch_bounds__(512, 2) void fused(const float* __restrict__ x,
                                                const u16* __restrict__ fragB,
                                                const u16* __restrict__ fragW,
                                                const float* __restrict__ b1,
                                                const float* __restrict__ gmm,
                                                const float* __restrict__ bta,
                                                float* __restrict__ out) {
  __shared__ __align__(16) char pool[114688];  // B: 2x32KB @0; A(x f32): 3x16KB @65536
  const int t = threadIdx.x;
  const int l = t & 63;
  const int w = t >> 6;       // 0..7
  const int wm = w >> 1;      // 0..3  m-slice (16 rows)
  const int wn = w & 1;       // 0..1  n-half (128 cols)
  const int m0 = blockIdx.x * 64;
  const float* xbase = x + (size_t)m0 * L_DIM;
  char* const bufA = pool + 65536;

  // ---- prologue: issue x(0), B(0), x(1) — order pinned for vmcnt counting ----
#pragma unroll
  for (int i = 0; i < 2; ++i) {
    const int R = (w * 2 + i) * 4 + (l >> 4);
    const int c16 = (l & 15) ^ PERM4(R);
    gload_lds16(xbase + (size_t)R * L_DIM + c16 * 4, bufA + (w * 2 + i) * 1024);
  }
  __builtin_amdgcn_sched_barrier(0);
#pragma unroll
  for (int i = 0; i < 4; ++i) {
    const int j = w * 4 + i;
    gload_lds16(fragB + (size_t)j * 512 + l * 8, pool + j * 1024);
  }
  __builtin_amdgcn_sched_barrier(0);
#pragma unroll
  for (int i = 0; i < 2; ++i) {
    const int R = (w * 2 + i) * 4 + (l >> 4);
    const int c16 = (l & 15) ^ PERM4(R);
    gload_lds16(xbase + (size_t)R * L_DIM + 64 + c16 * 4,
                bufA + 16384 + (w * 2 + i) * 1024);
  }
  __builtin_amdgcn_sched_barrier(0);

  f32x4 acc[8] = {};
  const int arow = wm * 16 + (l & 15);
  const int p4 = PERM4(arow);

  for (int s = 0; s < 64; ++s) {
    // steady queue at top: [x(s):2, B(s):4, x(s+1):2] -> wait all but x(s+1)
    if (s == 63) asm volatile("s_waitcnt vmcnt(0)" ::: "memory");
    else         asm volatile("s_waitcnt vmcnt(2)" ::: "memory");
    __builtin_amdgcn_s_barrier();
    __builtin_amdgcn_sched_barrier(0);
    if (s < 63) {                                    // B(s+1)
      const u16* srcB = fragB + (size_t)(s + 1) * 32 * 512;
#pragma unroll
      for (int i = 0; i < 4; ++i) {
        const int j = w * 4 + i;
        gload_lds16(srcB + (size_t)j * 512 + l * 8,
                    pool + ((s + 1) & 1) * 32768 + j * 1024);
      }
    }
    __builtin_amdgcn_sched_barrier(0);               // pin: B group before x group
    if (s < 62) {                                    // x(s+2)
      const int nx = s + 2;
#pragma unroll
      for (int i = 0; i < 2; ++i) {
        const int R = (w * 2 + i) * 4 + (l >> 4);
        const int c16 = (l & 15) ^ PERM4(R);
        gload_lds16(xbase + (size_t)R * L_DIM + nx * 64 + c16 * 4,
                    bufA + (nx % 3) * 16384 + (w * 2 + i) * 1024);
      }
    }
    __builtin_amdgcn_sched_barrier(0);               // pin: all issues before compute
    // compute stage s
    const char* bA = bufA + (s % 3) * 16384;
    const char* bB = pool + (s & 1) * 32768;
#pragma unroll
    for (int ks = 0; ks < 2; ++ks) {
      const int gs = ks * 8 + (l >> 4) * 2;
      const float4 a0 = *(const float4*)(bA + arow * 256 + ((gs ^ p4) * 16));
      const float4 a1 = *(const float4*)(bA + arow * 256 + (((gs + 1) ^ p4) * 16));
      short8 af;
      af[0] = (short)f2bf(a0.x); af[1] = (short)f2bf(a0.y);
      af[2] = (short)f2bf(a0.z); af[3] = (short)f2bf(a0.w);
      af[4] = (short)f2bf(a1.x); af[5] = (short)f2bf(a1.y);
      af[6] = (short)f2bf(a1.z); af[7] = (short)f2bf(a1.w);
#pragma unroll
      for (int nt = 0; nt < 8; ++nt) {
        const short8 bf = *(const short8*)(bB + (ks * 16 + wn * 8 + nt) * 1024 + l * 16);
        acc[nt] = __builtin_amdgcn_mfma_f32_16x16x32_bf16(af, bf, acc[nt], 0, 0, 0);
      }
    }
    asm volatile("s_waitcnt lgkmcnt(0)" ::: "memory");
    __builtin_amdgcn_s_barrier();
  }

  // ---- GEMM2 prologue: issue W(0) (L2-resident) while writing h tile to LDS ----
#pragma unroll
  for (int i = 0; i < 4; ++i) {
    const int j = w * 4 + i;
    gload_lds16(fragW + (size_t)j * 512 + l * 8, pool + j * 1024);
  }
  // h tile (bf16, XOR-swizzled 16B slots) into bufA[0..32KB)
  const int hrow_base = wm * 16 + ((l >> 4) << 2);
#pragma unroll
  for (int rr = 0; rr < 4; ++rr) {
    const int row = hrow_base + rr;
#pragma unroll
    for (int nt = 0; nt < 8; ++nt) {
      const int col = wn * 128 + nt * 16 + (l & 15);
      const int ls = (col >> 3) ^ (row & 15);
      *(u16*)(bufA + row * 512 + ls * 16 + (col & 7) * 2) = f2bf(acc[nt][rr]);
    }
  }
  asm volatile("s_waitcnt lgkmcnt(0)" ::: "memory");
  __builtin_amdgcn_s_barrier();

  f32x4 acc2[8] = {};
  for (int kt = 0; kt < 4; ++kt) {
    asm volatile("s_waitcnt vmcnt(0)" ::: "memory");   // W(kt) landed (order-independent)
    __builtin_amdgcn_s_barrier();
    __builtin_amdgcn_sched_barrier(0);
    if (kt < 3) {
      const u16* srcW = fragW + (size_t)(kt + 1) * 32 * 512;
#pragma unroll
      for (int i = 0; i < 4; ++i) {
        const int j = w * 4 + i;
        gload_lds16(srcW + (size_t)j * 512 + l * 8,
                    pool + ((kt + 1) & 1) * 32768 + j * 1024);
      }
    }
    __builtin_amdgcn_sched_barrier(0);
    const char* bW = pool + (kt & 1) * 32768;
#pragma unroll
    for (int ksi = 0; ksi < 2; ++ksi) {
      const int ks = kt * 2 + ksi;                     // 0..7
      const short8 af = *(const short8*)(
          bufA + arow * 512 + (((ks * 4 + (l >> 4)) ^ (arow & 15)) * 16));
#pragma unroll
      for (int nt = 0; nt < 8; ++nt) {
        const short8 bf = *(const short8*)(bW + (ksi * 16 + wn * 8 + nt) * 1024 + l * 16);
        acc2[nt] = __builtin_amdgcn_mfma_f32_16x16x32_bf16(af, bf, acc2[nt], 0, 0, 0);
      }
    }
    asm volatile("s_waitcnt lgkmcnt(0)" ::: "memory");
    __builtin_amdgcn_s_barrier();
  }

  // ---- bias + relu + LN + store ----
  float bv[8];
#pragma unroll
  for (int nt = 0; nt < 8; ++nt) bv[nt] = b1[wn * 128 + nt * 16 + (l & 15)];
  float s4[4], q4[4];
#pragma unroll
  for (int rr = 0; rr < 4; ++rr) {
    float s = 0.f, q = 0.f;
#pragma unroll
    for (int nt = 0; nt < 8; ++nt) {
      const float v = fmaxf(acc2[nt][rr] + bv[nt], 0.f);
      acc2[nt][rr] = v; s += v; q += v * v;
    }
#pragma unroll
    for (int m = 1; m < 16; m <<= 1) { s += __shfl_xor(s, m); q += __shfl_xor(q, m); }
    s4[rr] = s; q4[rr] = q;
  }
  float* lnred = (float*)pool;                 // [2][64][2] f32, B-pool is free now
  if ((l & 15) == 0) {
#pragma unroll
    for (int rr = 0; rr < 4; ++rr) {
      const int row = hrow_base + rr;
      lnred[(wn * 64 + row) * 2 + 0] = s4[rr];
      lnred[(wn * 64 + row) * 2 + 1] = q4[rr];
    }
  }
  __syncthreads();
  float gg[8], bb[8];
#pragma unroll
  for (int nt = 0; nt < 8; ++nt) {
    const int col = wn * 128 + nt * 16 + (l & 15);
    gg[nt] = gmm[col]; bb[nt] = bta[col];
  }
#pragma unroll
  for (int rr = 0; rr < 4; ++rr) {
    const int row = hrow_base + rr;
    const float S = lnred[row * 2 + 0] + lnred[(64 + row) * 2 + 0];
    const float Q = lnred[row * 2 + 1] + lnred[(64 + row) * 2 + 1];
    const float mu = S * (1.0f / 256.0f);
    const float rstd = rsqrtf(Q * (1.0f / 256.0f) - mu * mu + LN_EPS);
    float* op = out + (size_t)(m0 + row) * H_DIM;
#pragma unroll
    for (int nt = 0; nt < 8; ++nt) {
      const int col = wn * 128 + nt * 16 + (l & 15);
      op[col] = gg[nt] * (acc2[nt][rr] - mu) * rstd + bb[nt];
    }
  }
}

extern "C" void kernel_launch(void* const* d_in, const int* in_sizes, int n_in,
                              void* d_out, int out_size, void* d_ws, size_t ws_size,
                              hipStream_t stream) {
  const float* x    = (const float*)d_in[0];
  const float* emb  = (const float*)d_in[1];
  const float* W1   = (const float*)d_in[2];
  const float* b1   = (const float*)d_in[3];
  const float* gmm  = (const float*)d_in[4];
  const float* bta  = (const float*)d_in[5];
  const int*   gidx = (const int*)d_in[6];
  float* out = (float*)d_out;

  char* ws = (char*)d_ws;
  u16* fragB = (u16*)ws;                                   // [128 ksteps][16 nt][64][8] = 2 MB
  u16* fragW = (u16*)(ws + (size_t)H_DIM * L_DIM * 2);     // [8 ksteps][16 nt][64][8] = 128 KB

  prep_frag<<<512, 256, 0, stream>>>(emb, gidx, fragB);    // 2048 frags
  prep_frag<<<32, 256, 0, stream>>>(W1, nullptr, fragW);   // 128 frags
  fused<<<256, 512, 0, stream>>>(x, fragB, fragW, b1, gmm, bta, out);
}

// Round 7
// 104.766 us; speedup vs baseline: 1.3774x; 1.0755x over previous
//
#include <hip/hip_runtime.h>
#include <stdint.h>

#define B_DIM 16384
#define L_DIM 4096
#define H_DIM 256
#define LN_EPS 1e-5f
// bijective 4-bit slot permutation from the low 4 row bits
#define PERM4(r) ((((r) & 7) << 1) | (((r) >> 3) & 1))

typedef unsigned short u16;
typedef __attribute__((ext_vector_type(4))) float f32x4;
typedef __attribute__((ext_vector_type(8))) short short8;

__device__ __forceinline__ u16 f2bf(float f) {
  union { float f; uint32_t u; } v; v.f = f;
  uint32_t u = v.u;
  u += 0x7FFFu + ((u >> 16) & 1u);   // round-to-nearest-even
  return (u16)(u >> 16);
}

__device__ __forceinline__ void gload_lds16(const void* g, void* l) {
  __builtin_amdgcn_global_load_lds((const __attribute__((address_space(1))) void*)g,
                                   (__attribute__((address_space(3))) void*)l, 16, 0, 0);
}

// Fragment-major prep (gathered emb / plain W1):
// frag = kstep*16 + nt;  dst[frag][lane][j] = bf16(src[row][nt*16 + (lane&15)])
// row = idx ? idx[kstep*32 + (lane>>4)*8 + j] : (kstep*32 + (lane>>4)*8 + j)
__global__ __launch_bounds__(256) void prep_frag(const float* __restrict__ src,
                                                 const int* __restrict__ idx,
                                                 u16* __restrict__ dst) {
  const int t = threadIdx.x;
  const int l = t & 63;
  const int w = t >> 6;
  const int frag = blockIdx.x * 4 + w;
  const int kstep = frag >> 4;
  const int nt = frag & 15;
  const int n = nt * 16 + (l & 15);
  const int kbase = kstep * 32 + (l >> 4) * 8;
  short8 v;
#pragma unroll
  for (int j = 0; j < 8; ++j) {
    const int k = kbase + j;
    const int g = idx ? idx[k] : k;
    v[j] = (short)f2bf(src[(size_t)g * H_DIM + n]);
  }
  *reinterpret_cast<short8*>(dst + ((size_t)frag * 64 + l) * 8) = v;
}

// Fused: h = x @ feat (bf16 MFMA, K=4096), then out = LN(relu(h @ W1 + b1)).
// BM=32, 256 thr = 4 waves (wm 0..1 x wn 0..1): wave owns 16 rows x 128 cols.
// LDS exactly 80KB -> 2 blocks/CU (grid 512): cross-block wave overlap hides
// the per-stage vmcnt(0)+barrier drains (R6 at 1 block/CU was latency-bound:
// MfmaUtil 9.5, VALUBusy 12.8, HBM 13% -- all idle).
// x: global_load_lds dbuf (source pre-PERM4-swizzled 16B slots; swizzled
// float4 reads back, fp32->bf16 in regs). B: fragment-major dbuf, linear.
// GEMM2: h tile lives in LDS only; W1 fragment-major 4-stage loop; LN fused.
__global__ __launch_bounds__(256, 2) void fused(const float* __restrict__ x,
                                                const u16* __restrict__ fragB,
                                                const u16* __restrict__ fragW,
                                                const float* __restrict__ b1,
                                                const float* __restrict__ gmm,
                                                const float* __restrict__ bta,
                                                float* __restrict__ out) {
  __shared__ __align__(16) char pool[81920];   // B: 2x32KB @0; A(x f32): 2x8KB @65536
  const int t = threadIdx.x;
  const int l = t & 63;
  const int w = t >> 6;       // 0..3
  const int wm = w >> 1;      // 0..1  m-slice (16 rows)
  const int wn = w & 1;       // 0..1  n-half (128 cols)
  const int m0 = blockIdx.x * 32;
  const float* xbase = x + (size_t)m0 * L_DIM;
  char* const bufA = pool + 65536;

  // ---- prologue: issue stage-0 x + B into buf0 ----
#pragma unroll
  for (int i = 0; i < 2; ++i) {
    const int R = (w * 2 + i) * 4 + (l >> 4);            // 0..31
    const int c16 = (l & 15) ^ PERM4(R);
    gload_lds16(xbase + (size_t)R * L_DIM + c16 * 4, bufA + (w * 2 + i) * 1024);
  }
#pragma unroll
  for (int i = 0; i < 8; ++i) {
    const int j = w * 8 + i;                             // 0..31
    gload_lds16(fragB + (size_t)j * 512 + l * 8, pool + j * 1024);
  }

  f32x4 acc[8] = {};
  const int arow = wm * 16 + (l & 15);                   // 0..31
  const int p4 = PERM4(arow);

  for (int s = 0; s < 64; ++s) {
    asm volatile("s_waitcnt vmcnt(0)" ::: "memory");     // stage-s staging done
    __builtin_amdgcn_s_barrier();
    __builtin_amdgcn_sched_barrier(0);
    if (s < 63) {                                        // issue stage s+1
      const int nb = (s + 1) & 1;
      const u16* srcB = fragB + (size_t)(s + 1) * 32 * 512;
#pragma unroll
      for (int i = 0; i < 8; ++i) {
        const int j = w * 8 + i;
        gload_lds16(srcB + (size_t)j * 512 + l * 8, pool + nb * 32768 + j * 1024);
      }
#pragma unroll
      for (int i = 0; i < 2; ++i) {
        const int R = (w * 2 + i) * 4 + (l >> 4);
        const int c16 = (l & 15) ^ PERM4(R);
        gload_lds16(xbase + (size_t)R * L_DIM + (s + 1) * 64 + c16 * 4,
                    bufA + nb * 8192 + (w * 2 + i) * 1024);
      }
    }
    __builtin_amdgcn_sched_barrier(0);                   // pin: issues before compute
    // compute stage s from buf (s&1)
    const char* bA = bufA + (s & 1) * 8192;
    const char* bB = pool + (s & 1) * 32768;
#pragma unroll
    for (int ks = 0; ks < 2; ++ks) {
      const int gs = ks * 8 + (l >> 4) * 2;
      const float4 a0 = *(const float4*)(bA + arow * 256 + ((gs ^ p4) * 16));
      const float4 a1 = *(const float4*)(bA + arow * 256 + (((gs + 1) ^ p4) * 16));
      short8 af;
      af[0] = (short)f2bf(a0.x); af[1] = (short)f2bf(a0.y);
      af[2] = (short)f2bf(a0.z); af[3] = (short)f2bf(a0.w);
      af[4] = (short)f2bf(a1.x); af[5] = (short)f2bf(a1.y);
      af[6] = (short)f2bf(a1.z); af[7] = (short)f2bf(a1.w);
#pragma unroll
      for (int nt = 0; nt < 8; ++nt) {
        const short8 bf = *(const short8*)(bB + (ks * 16 + wn * 8 + nt) * 1024 + l * 16);
        acc[nt] = __builtin_amdgcn_mfma_f32_16x16x32_bf16(af, bf, acc[nt], 0, 0, 0);
      }
    }
    asm volatile("s_waitcnt lgkmcnt(0)" ::: "memory");   // reads done before next writes
    __builtin_amdgcn_s_barrier();
  }

  // ---- GEMM2 prologue: issue W(0) (L2-resident) while writing h tile to LDS ----
#pragma unroll
  for (int i = 0; i < 8; ++i) {
    const int j = w * 8 + i;
    gload_lds16(fragW + (size_t)j * 512 + l * 8, pool + j * 1024);
  }
  // h tile (bf16, XOR-swizzled 16B slots) into bufA (32 rows x 512B = 16KB)
  const int hrow_base = wm * 16 + ((l >> 4) << 2);
#pragma unroll
  for (int rr = 0; rr < 4; ++rr) {
    const int row = hrow_base + rr;
#pragma unroll
    for (int nt = 0; nt < 8; ++nt) {
      const int col = wn * 128 + nt * 16 + (l & 15);
      const int ls = (col >> 3) ^ (row & 15);
      *(u16*)(bufA + row * 512 + ls * 16 + (col & 7) * 2) = f2bf(acc[nt][rr]);
    }
  }
  asm volatile("s_waitcnt lgkmcnt(0)" ::: "memory");
  __builtin_amdgcn_s_barrier();

  f32x4 acc2[8] = {};
  for (int kt = 0; kt < 4; ++kt) {
    asm volatile("s_waitcnt vmcnt(0)" ::: "memory");     // W(kt) landed
    __builtin_amdgcn_s_barrier();
    __builtin_amdgcn_sched_barrier(0);
    if (kt < 3) {
      const u16* srcW = fragW + (size_t)(kt + 1) * 32 * 512;
#pragma unroll
      for (int i = 0; i < 8; ++i) {
        const int j = w * 8 + i;
        gload_lds16(srcW + (size_t)j * 512 + l * 8,
                    pool + ((kt + 1) & 1) * 32768 + j * 1024);
      }
    }
    __builtin_amdgcn_sched_barrier(0);
    const char* bW = pool + (kt & 1) * 32768;
#pragma unroll
    for (int ksi = 0; ksi < 2; ++ksi) {
      const int ks = kt * 2 + ksi;                       // 0..7
      const short8 af = *(const short8*)(
          bufA + arow * 512 + (((ks * 4 + (l >> 4)) ^ (arow & 15)) * 16));
#pragma unroll
      for (int nt = 0; nt < 8; ++nt) {
        const short8 bf = *(const short8*)(bW + (ksi * 16 + wn * 8 + nt) * 1024 + l * 16);
        acc2[nt] = __builtin_amdgcn_mfma_f32_16x16x32_bf16(af, bf, acc2[nt], 0, 0, 0);
      }
    }
    asm volatile("s_waitcnt lgkmcnt(0)" ::: "memory");
    __builtin_amdgcn_s_barrier();
  }

  // ---- bias + relu + LN + store ----
  float bv[8];
#pragma unroll
  for (int nt = 0; nt < 8; ++nt) bv[nt] = b1[wn * 128 + nt * 16 + (l & 15)];
  float s4[4], q4[4];
#pragma unroll
  for (int rr = 0; rr < 4; ++rr) {
    float s = 0.f, q = 0.f;
#pragma unroll
    for (int nt = 0; nt < 8; ++nt) {
      const float v = fmaxf(acc2[nt][rr] + bv[nt], 0.f);
      acc2[nt][rr] = v; s += v; q += v * v;
    }
#pragma unroll
    for (int m = 1; m < 16; m <<= 1) { s += __shfl_xor(s, m); q += __shfl_xor(q, m); }
    s4[rr] = s; q4[rr] = q;
  }
  float* lnred = (float*)pool;                 // [2][32][2] f32, B-pool free now
  if ((l & 15) == 0) {
#pragma unroll
    for (int rr = 0; rr < 4; ++rr) {
      const int row = hrow_base + rr;
      lnred[(wn * 32 + row) * 2 + 0] = s4[rr];
      lnred[(wn * 32 + row) * 2 + 1] = q4[rr];
    }
  }
  __syncthreads();
  float gg[8], bb[8];
#pragma unroll
  for (int nt = 0; nt < 8; ++nt) {
    const int col = wn * 128 + nt * 16 + (l & 15);
    gg[nt] = gmm[col]; bb[nt] = bta[col];
  }
#pragma unroll
  for (int rr = 0; rr < 4; ++rr) {
    const int row = hrow_base + rr;
    const float S = lnred[row * 2 + 0] + lnred[(32 + row) * 2 + 0];
    const float Q = lnred[row * 2 + 1] + lnred[(32 + row) * 2 + 1];
    const float mu = S * (1.0f / 256.0f);
    const float rstd = rsqrtf(Q * (1.0f / 256.0f) - mu * mu + LN_EPS);
    float* op = out + (size_t)(m0 + row) * H_DIM;
#pragma unroll
    for (int nt = 0; nt < 8; ++nt) {
      const int col = wn * 128 + nt * 16 + (l & 15);
      op[col] = gg[nt] * (acc2[nt][rr] - mu) * rstd + bb[nt];
    }
  }
}

extern "C" void kernel_launch(void* const* d_in, const int* in_sizes, int n_in,
                              void* d_out, int out_size, void* d_ws, size_t ws_size,
                              hipStream_t stream) {
  const float* x    = (const float*)d_in[0];
  const float* emb  = (const float*)d_in[1];
  const float* W1   = (const float*)d_in[2];
  const float* b1   = (const float*)d_in[3];
  const float* gmm  = (const float*)d_in[4];
  const float* bta  = (const float*)d_in[5];
  const int*   gidx = (const int*)d_in[6];
  float* out = (float*)d_out;

  char* ws = (char*)d_ws;
  u16* fragB = (u16*)ws;                                   // [128 ksteps][16 nt][64][8] = 2 MB
  u16* fragW = (u16*)(ws + (size_t)H_DIM * L_DIM * 2);     // [8 ksteps][16 nt][64][8] = 128 KB

  prep_frag<<<512, 256, 0, stream>>>(emb, gidx, fragB);    // 2048 frags
  prep_frag<<<32, 256, 0, stream>>>(W1, nullptr, fragW);   // 128 frags
  fused<<<512, 256, 0, stream>>>(x, fragB, fragW, b1, gmm, bta, out);
}